// Round 24
// baseline (105.906 us; speedup 1.0000x reference)
//
#include <hip/hip_runtime.h>

typedef __attribute__((ext_vector_type(8))) short bf16x8;
typedef __attribute__((ext_vector_type(4))) float f32x4;
typedef __attribute__((ext_vector_type(16))) float f32x16;
typedef __attribute__((ext_vector_type(4))) unsigned int u32x4;
typedef __attribute__((ext_vector_type(4))) unsigned short u16x4;

#define DEVFN static __device__ __forceinline__

DEVFN unsigned cvtpk(float lo, float hi) {
  unsigned r;
  asm("v_cvt_pk_bf16_f32 %0, %1, %2" : "=v"(r) : "v"(lo), "v"(hi));
  return r;
}
DEVFN unsigned short cvt1(float x) {
  unsigned r;
  asm("v_cvt_pk_bf16_f32 %0, %1, %1" : "=v"(r) : "v"(x));
  return (unsigned short)r;
}
DEVFN float fexp2(float x) {
  float r;
  asm("v_exp_f32 %0, %1" : "=v"(r) : "v"(x));
  return r;
}
DEVFN float bf2f(unsigned short s) { return __uint_as_float(((unsigned)s) << 16); }

DEVFN void gld16(const void* g, void* l) {
  __builtin_amdgcn_global_load_lds(
      (const __attribute__((address_space(1))) unsigned int*)g,
      (__attribute__((address_space(3))) unsigned int*)l, 16, 0, 0);
}

// barrier that orders LDS *reads* only: lgkm drain, leaves VMEM in flight
DEVFN void lds_read_barrier() {
  asm volatile("s_waitcnt lgkmcnt(0)" ::: "memory");
  __builtin_amdgcn_sched_barrier(0);
  __builtin_amdgcn_s_barrier();
  __builtin_amdgcn_sched_barrier(0);
}

// fused: mask packing (blocks 0..32767) + 5 weight-matrix f32->bf16 casts
__global__ __launch_bounds__(256, 8) void prep_misc(
    const int* __restrict__ m, unsigned long long* __restrict__ mb,
    const float* __restrict__ w0, const float* __restrict__ w1,
    const float* __restrict__ w2, const float* __restrict__ w3,
    unsigned short* __restrict__ w4dst,
    const float* __restrict__ wout, unsigned short* __restrict__ woutdst) {
  int bid = blockIdx.x;
  int tid = threadIdx.x;
  if (bid < 32768) {
    int word = bid * 4 + (tid >> 6);
    int lane = tid & 63;
    int v = m[(size_t)(word >> 4) * 1024 + (word & 15) * 64 + lane];
    unsigned long long bal = __ballot(v != 0);
    if (lane == 0) mb[word] = bal;
    return;
  }
  int pid = bid - 32768;  // 0..639
  const float* s;
  unsigned short* d;
  size_t off;
  if (pid < 512) {
    int y = pid >> 7;
    s = (y == 0) ? w0 : (y == 1) ? w1 : (y == 2) ? w2 : w3;
    d = w4dst + (size_t)y * 262144;
    off = (size_t)(pid & 127) * 2048 + (size_t)tid * 8;
  } else {
    s = wout;
    d = woutdst;
    off = (size_t)(pid - 512) * 2048 + (size_t)tid * 8;
  }
  float4 a = *(const float4*)(s + off);
  float4 b = *(const float4*)(s + off + 4);
  uint4 o;
  o.x = cvtpk(a.x, a.y); o.y = cvtpk(a.z, a.w);
  o.z = cvtpk(b.x, b.y); o.w = cvtpk(b.z, b.w);
  *(uint4*)(d + off) = o;
}

// ---- qkvp GEMM: fused f32-A cast, tile 128x256, BK=64, 8 waves, A single-
// buffered reg staging, B double-buffered gld16. T4 counted-vmcnt at
// barrier-2: only B(k+1) retired; A(k+2)/B(k+2) stay in flight.
__global__ __launch_bounds__(512, 2) void gemm_qkvp(
    const float* __restrict__ A0, const float* __restrict__ A1,
    const float* __restrict__ A2, const float* __restrict__ A3,
    const unsigned short* __restrict__ Wb, const float* __restrict__ b0,
    const float* __restrict__ b1, const float* __restrict__ b2,
    unsigned short* __restrict__ qout, float* __restrict__ cache,
    unsigned short* __restrict__ vtout, unsigned short* __restrict__ pout) {
  __shared__ alignas(16) char Als[128 * 128];
  __shared__ alignas(16) char Bls[2][256 * 128];
  const int tid = threadIdx.x;
  const int lane = tid & 63, w = tid >> 6;
  const int wr = (w >> 2) * 64, wc = (w & 3) * 64;
  const int lg = lane >> 4, lr = lane & 15;
  int id = blockIdx.x;
  int xcd = id & 7, j = id >> 3;
  const int n0 = (j & 1) * 256;
  const int mz = (j >> 1) & 3;
  const int m0 = (xcd * 8 + (j >> 3)) * 128;
  const float* Ap = (mz == 1) ? A1 : (mz == 2) ? A2 : (mz == 3) ? A3 : A0;
  const unsigned short* Wp = Wb + (size_t)mz * 262144;
  const float* bias = (mz == 0) ? b0 : (mz == 1) ? b1 : (mz == 2) ? b2 : nullptr;

  float4 ra[4];
  auto loadA = [&](int k0) {
#pragma unroll
    for (int rep = 0; rep < 2; rep++) {
      int cid = rep * 512 + tid;
      int row = cid >> 3, c = cid & 7;
      const float* src = Ap + (size_t)(m0 + row) * 512 + k0 + c * 8;
      ra[rep * 2] = *(const float4*)(src);
      ra[rep * 2 + 1] = *(const float4*)(src + 4);
    }
  };
  auto writeA = [&]() {
#pragma unroll
    for (int rep = 0; rep < 2; rep++) {
      int cid = rep * 512 + tid;
      int row = cid >> 3, c = cid & 7;
      uint4 o;
      o.x = cvtpk(ra[rep * 2].x, ra[rep * 2].y);
      o.y = cvtpk(ra[rep * 2].z, ra[rep * 2].w);
      o.z = cvtpk(ra[rep * 2 + 1].x, ra[rep * 2 + 1].y);
      o.w = cvtpk(ra[rep * 2 + 1].z, ra[rep * 2 + 1].w);
      *(uint4*)(Als + row * 128 + ((c ^ (row & 7)) << 4)) = o;
    }
  };
  auto stageB = [&](int buf, int k0) {
#pragma unroll
    for (int rep = 0; rep < 4; rep++) {
      int cid = rep * 512 + tid;
      int row = cid >> 3, c = cid & 7;
      gld16(Wp + (size_t)(n0 + row) * 512 + k0 + ((c ^ (row & 7)) << 3),
            Bls[buf] + ((rep * 512 + (w << 6)) << 4));
    }
  };

  f32x4 acc[4][4];
#pragma unroll
  for (int i = 0; i < 4; i++)
#pragma unroll
    for (int jj = 0; jj < 4; jj++) acc[i][jj] = (f32x4)(0.f);

  // prologue: Als=A0; ra=A1; B0,B1 staged; full drain.
  loadA(0);
  writeA();
  stageB(0, 0);
  loadA(64);
  stageB(1, 64);
  __syncthreads();

  for (int k = 0; k < 8; ++k) {
#pragma unroll
    for (int ks = 0; ks < 2; ks++) {
      bf16x8 af[4], bfr[4];
#pragma unroll
      for (int i = 0; i < 4; i++) {
        int row = wr + i * 16 + lr;
        af[i] = *(const bf16x8*)(Als + row * 128 + (((ks * 4 + lg) ^ (row & 7)) << 4));
      }
#pragma unroll
      for (int jj = 0; jj < 4; jj++) {
        int row = wc + jj * 16 + lr;
        bfr[jj] = *(const bf16x8*)(Bls[k & 1] + row * 128 + (((ks * 4 + lg) ^ (row & 7)) << 4));
      }
#pragma unroll
      for (int i = 0; i < 4; i++)
#pragma unroll
        for (int jj = 0; jj < 4; jj++)
          acc[i][jj] = __builtin_amdgcn_mfma_f32_16x16x32_bf16(af[i], bfr[jj],
                                                               acc[i][jj], 0, 0, 0);
    }
    if (k < 7) {
      lds_read_barrier();            // Als/Bls[k&1] reads retired; VMEM in flight
      writeA();                      // A(k+1) -> Als (counted wait on ra only)
      if (k + 2 <= 7) {
        loadA((k + 2) * 64);         // ra = A(k+2)
        stageB(k & 1, (k + 2) * 64); // B(k+2) -> freed buffer
      }
      asm volatile("s_waitcnt lgkmcnt(0)" ::: "memory");  // ds_writes visible
      __builtin_amdgcn_sched_barrier(0);
      // retire exactly B(k+1); keep A(k+2)+B(k+2) (8 ops) in flight
      if (k < 6) {
        asm volatile("s_waitcnt vmcnt(8)" ::: "memory");
      } else {
        asm volatile("s_waitcnt vmcnt(0)" ::: "memory");
      }
      __builtin_amdgcn_sched_barrier(0);
      __builtin_amdgcn_s_barrier();
      __builtin_amdgcn_sched_barrier(0);
    }
  }

#pragma unroll
  for (int i = 0; i < 4; i++) {
#pragma unroll
    for (int jj = 0; jj < 4; jj++) {
      int colg = n0 + wc + jj * 16 + lr;
      float bc = bias ? bias[colg] : 0.f;
      int rbase = m0 + wr + i * 16 + lg * 4;
      int b = rbase >> 10, t = rbase & 1023, h = colg >> 6, dk = colg & 63;
      size_t bht = (size_t)(b * 8 + h) * 1024 + t;
      if (mz == 0) {
#pragma unroll
        for (int r = 0; r < 4; r++) qout[(bht + r) * 64 + dk] = cvt1(acc[i][jj][r] + bc);
      } else if (mz == 1) {
#pragma unroll
        for (int r = 0; r < 4; r++) cache[(bht + r) * 128 + dk] = acc[i][jj][r] + bc;
      } else if (mz == 3) {
#pragma unroll
        for (int r = 0; r < 4; r++) pout[(bht + r) * 64 + dk] = cvt1(acc[i][jj][r]);
      } else {
        float vv[4];
#pragma unroll
        for (int r = 0; r < 4; r++) {
          vv[r] = acc[i][jj][r] + bc;
          cache[(bht + r) * 128 + 64 + dk] = vv[r];
        }
        uint2 pv;
        pv.x = cvtpk(vv[0], vv[1]);
        pv.y = cvtpk(vv[2], vv[3]);
        *(uint2*)(vtout + ((size_t)(b * 8 + h) * 64 + dk) * 1024 + t) = pv;
      }
    }
  }
}

// ---- out-GEMM (R23 exact): 64x128 tile, 4 waves, lgkm-only barrier1
__global__ __launch_bounds__(256, 4) void gemm_out(
    const unsigned short* __restrict__ Ab, const unsigned short* __restrict__ Wp,
    const float* __restrict__ bias, float* __restrict__ fout) {
  __shared__ alignas(16) char Als[64 * 128];
  __shared__ alignas(16) char Bls[2][128 * 128];
  const int tid = threadIdx.x;
  const int lane = tid & 63, w = tid >> 6;
  const int wr = (w >> 1) * 32, wc = (w & 1) * 64;
  const int lg = lane >> 4, lr = lane & 15;
  const int m0 = blockIdx.x * 64, n0 = blockIdx.y * 128;

  auto stageA = [&](int k0) {
#pragma unroll
    for (int rep = 0; rep < 2; rep++) {
      int cid = rep * 256 + tid;
      int row = cid >> 3, c = cid & 7;
      gld16(Ab + (size_t)(m0 + row) * 512 + k0 + ((c ^ (row & 7)) << 3),
            Als + ((rep * 256 + (w << 6)) << 4));
    }
  };
  auto stageB = [&](int buf, int k0) {
#pragma unroll
    for (int rep = 0; rep < 4; rep++) {
      int cid = rep * 256 + tid;
      int row = cid >> 3, c = cid & 7;
      gld16(Wp + (size_t)(n0 + row) * 512 + k0 + ((c ^ (row & 7)) << 3),
            Bls[buf] + ((rep * 256 + (w << 6)) << 4));
    }
  };

  f32x4 acc[2][4];
#pragma unroll
  for (int i = 0; i < 2; i++)
#pragma unroll
    for (int j = 0; j < 4; j++) acc[i][j] = (f32x4)(0.f);

  stageA(0);
  stageB(0, 0);
  __syncthreads();
  int cur = 0;
  for (int k0 = 0; k0 < 512; k0 += 64) {
    bool more = (k0 + 64 < 512);
    if (more) stageB(cur ^ 1, k0 + 64);
#pragma unroll
    for (int ks = 0; ks < 2; ks++) {
      bf16x8 af[2], bfr[4];
#pragma unroll
      for (int i = 0; i < 2; i++) {
        int row = wr + i * 16 + lr;
        af[i] = *(const bf16x8*)(Als + row * 128 + (((ks * 4 + lg) ^ (row & 7)) << 4));
      }
#pragma unroll
      for (int j = 0; j < 4; j++) {
        int row = wc + j * 16 + lr;
        bfr[j] = *(const bf16x8*)(Bls[cur] + row * 128 + (((ks * 4 + lg) ^ (row & 7)) << 4));
      }
#pragma unroll
      for (int i = 0; i < 2; i++)
#pragma unroll
        for (int j = 0; j < 4; j++)
          acc[i][j] = __builtin_amdgcn_mfma_f32_16x16x32_bf16(af[i], bfr[j],
                                                              acc[i][j], 0, 0, 0);
    }
    if (more) {
      lds_read_barrier();
      stageA(k0 + 64);
      __syncthreads();
      cur ^= 1;
    }
  }

#pragma unroll
  for (int i = 0; i < 2; i++) {
#pragma unroll
    for (int j = 0; j < 4; j++) {
      int colg = n0 + wc + j * 16 + lr;
      float bc = bias[colg];
#pragma unroll
      for (int r = 0; r < 4; r++) {
        int rowg = m0 + wr + i * 16 + lg * 4 + r;
        fout[(size_t)rowg * 512 + colg] = acc[i][j][r] + bc;
      }
    }
  }
}

__global__ __launch_bounds__(256, 4) void fuse_kp(
    const float* __restrict__ kcache, unsigned short* __restrict__ kp,
    const float* __restrict__ ub, const float* __restrict__ vb,
    float* __restrict__ cb) {
  int tid = threadIdx.x;
  int row = blockIdx.x * 16 + (tid >> 4);
  int g = tid & 15;
  int h = (row >> 10) & 7;
  float4 k4 = *(const float4*)(kcache + (size_t)row * 128 + g * 4);
  u16x4 p4 = *(const u16x4*)(kp + (size_t)row * 64 + g * 4);
  float4 uu = *(const float4*)(ub + h * 64 + g * 4);
  float4 vv = *(const float4*)(vb + h * 64 + g * 4);
  float kf[4] = {k4.x, k4.y, k4.z, k4.w};
  float uf[4] = {uu.x, uu.y, uu.z, uu.w};
  float vf[4] = {vv.x, vv.y, vv.z, vv.w};
  float part = 0.f;
  float s[4];
#pragma unroll
  for (int j = 0; j < 4; j++) {
    float pf = bf2f((unsigned short)p4[j]);
    s[j] = kf[j] + pf;
    part += uf[j] * kf[j] + vf[j] * pf;
  }
  uint2 o;
  o.x = cvtpk(s[0], s[1]);
  o.y = cvtpk(s[2], s[3]);
  *(uint2*)(kp + (size_t)row * 64 + g * 4) = o;
#pragma unroll
  for (int sft = 1; sft < 16; sft <<= 1) part += __shfl_xor(part, sft, 64);
  if (g == 0) cb[row] = part;
}

// flash attn, m214-style (unchanged from R12-R23)
__global__ __launch_bounds__(256, 2) void attn_kernel(
    const unsigned short* __restrict__ qw, const unsigned short* __restrict__ kpw,
    const unsigned short* __restrict__ vtw, const float* __restrict__ cb,
    const unsigned long long* __restrict__ mbits, unsigned short* __restrict__ ow) {
  __shared__ alignas(16) char KPls[2][128 * 128];
  __shared__ alignas(16) char VTls[2][64 * 256];
  __shared__ alignas(16) float cvLS[1024];
  __shared__ alignas(16) float lsLS[4][32];

  const int tid = threadIdx.x;
  const int lane = tid & 63, w = tid >> 6;
  const int hi = lane >> 5, q5 = lane & 31;
  const int l = blockIdx.x;
  const int bh = (l & 7) * 8 + ((l >> 3) >> 3);
  const int t0 = ((l >> 3) & 7) * 128;
  const int b = bh >> 3;
  const int h = bh & 7;
  const float NEG = -3.0e38f;
  const float SC = 0.125f * 1.44269504088896f;
  const float MREF = 24.0f;

#pragma unroll
  for (int i = 0; i < 4; i++)
    cvLS[i * 256 + tid] = cb[(size_t)bh * 1024 + i * 256 + tid] * SC - MREF;

  const int qg = t0 + w * 32 + q5;
  const size_t qrow = (size_t)bh * 1024 + qg;
  bf16x8 qf[4];
#pragma unroll
  for (int ks = 0; ks < 4; ks++)
    qf[ks] = *(const bf16x8*)(qw + qrow * 64 + ks * 16 + hi * 8);

  bool wave_full;
  {
    unsigned long long accm = ~0ull;
#pragma unroll
    for (int j = 0; j < 8; j++)
      accm &= mbits[((size_t)b * 1024 + qg) * 16 + hi * 8 + j];
    wave_full = __all(accm == ~0ull);
  }

  f32x16 oacc[2];
#pragma unroll
  for (int dt = 0; dt < 2; dt++) oacc[dt] = (f32x16)(0.f);
  float mrow = 0.f, lsum = 0.f;

  auto stage = [&](int buf, int s0) {
    const size_t kr0 = (size_t)bh * 1024 + s0;
#pragma unroll
    for (int p = 0; p < 4; p++) {
      int row = p * 32 + (tid >> 3), c = tid & 7;
      gld16(kpw + (kr0 + row) * 64 + ((c ^ (row & 7)) << 3),
            KPls[buf] + p * 4096 + w * 1024);
    }
#pragma unroll
    for (int p = 0; p < 4; p++) {
      int row = p * 16 + (tid >> 4), c = tid & 15;
      gld16(vtw + ((size_t)bh * 64 + row) * 1024 + s0 + ((c ^ (row & 15)) << 3),
            VTls[buf] + p * 4096 + w * 1024);
    }
  };

  stage(0, 0);
  __syncthreads();
  int cur = 0;
  for (int it = 0; it < 8; ++it) {
    const int s0 = it * 128;
    if (it < 7) stage(cur ^ 1, s0 + 128);

#pragma unroll
    for (int t = 0; t < 4; t++) {
      f32x16 sacc = (f32x16)(0.f);
      const int arow = t * 32 + q5;
      __builtin_amdgcn_s_setprio(1);
#pragma unroll
      for (int ks = 0; ks < 4; ks++) {
        bf16x8 kf = *(const bf16x8*)(KPls[cur] + arow * 128 +
                                     (((ks * 2 + hi) ^ (arow & 7)) << 4));
        sacc = __builtin_amdgcn_mfma_f32_32x32x16_bf16(kf, qf[ks], sacc, 0, 0, 0);
      }
      __builtin_amdgcn_s_setprio(0);

      float p[16];
      if (wave_full) {
        float ls = 0.f;
#pragma unroll
        for (int rb = 0; rb < 4; rb++) {
          f32x4 cv4 = *(const f32x4*)(cvLS + s0 + t * 32 + rb * 8 + hi * 4);
#pragma unroll
          for (int j = 0; j < 4; j++) {
            int reg = rb * 4 + j;
            p[reg] = fexp2(fmaf(sacc[reg], SC, cv4[j]));
            ls += p[reg];
          }
        }
        lsum += ls;
      } else {
        unsigned long long mw =
            mbits[((size_t)b * 1024 + qg) * 16 + ((s0 + t * 32) >> 6)];
        const int bbase = (t & 1) * 32;
        float s_[16];
        float mx = NEG;
#pragma unroll
        for (int rb = 0; rb < 4; rb++) {
          f32x4 cv4 = *(const f32x4*)(cvLS + s0 + t * 32 + rb * 8 + hi * 4);
#pragma unroll
          for (int j = 0; j < 4; j++) {
            int reg = rb * 4 + j;
            s_[reg] = fmaf(sacc[reg], SC, cv4[j]);
            if ((mw >> (bbase + rb * 8 + hi * 4 + j)) & 1ull)
              mx = fmaxf(mx, s_[reg]);
          }
        }
        mx = fmaxf(mx, __shfl_xor(mx, 32, 64));
        float mn = fmaxf(mrow, mx);
        float sc = (mn == mrow) ? 1.f : fexp2(mrow - mn);
        mrow = mn;
        lsum *= sc;
#pragma unroll
        for (int rb = 0; rb < 4; rb++)
#pragma unroll
          for (int j = 0; j < 4; j++) {
            int reg = rb * 4 + j;
            bool on = (mw >> (bbase + rb * 8 + hi * 4 + j)) & 1ull;
            p[reg] = on ? fexp2(s_[reg] - mn) : 0.f;
            lsum += p[reg];
          }
        if (lane < 32) lsLS[w][q5] = sc;
        asm volatile("s_waitcnt lgkmcnt(0)" ::: "memory");
        __builtin_amdgcn_sched_barrier(0);
#pragma unroll
        for (int rb = 0; rb < 4; rb++) {
          f32x4 s4 = *(const f32x4*)(&lsLS[w][rb * 8 + hi * 4]);
#pragma unroll
          for (int j = 0; j < 4; j++) {
#pragma unroll
            for (int dt = 0; dt < 2; dt++) oacc[dt][rb * 4 + j] *= s4[j];
          }
        }
      }

#pragma unroll
      for (int ks16 = 0; ks16 < 2; ks16++) {
        unsigned a0 = cvtpk(p[ks16 * 8 + 0], p[ks16 * 8 + 1]);
        unsigned a1 = cvtpk(p[ks16 * 8 + 2], p[ks16 * 8 + 3]);
        unsigned b0 = cvtpk(p[ks16 * 8 + 4], p[ks16 * 8 + 5]);
        unsigned b1 = cvtpk(p[ks16 * 8 + 6], p[ks16 * 8 + 7]);
        unsigned xa0 = __shfl_xor(a0, 32, 64);
        unsigned xa1 = __shfl_xor(a1, 32, 64);
        unsigned xb0 = __shfl_xor(b0, 32, 64);
        unsigned xb1 = __shfl_xor(b1, 32, 64);
        u32x4 pk4;
        pk4.x = hi ? xb0 : a0;
        pk4.y = hi ? xb1 : a1;
        pk4.z = hi ? b0 : xa0;
        pk4.w = hi ? b1 : xa1;
        bf16x8 af = __builtin_bit_cast(bf16x8, pk4);
        __builtin_amdgcn_s_setprio(1);
#pragma unroll
        for (int dt = 0; dt < 2; dt++) {
          int vrow = dt * 32 + q5;
          int vc = t * 4 + ks16 * 2 + hi;
          bf16x8 vf = *(const bf16x8*)(VTls[cur] + vrow * 256 +
                                       ((vc ^ (vrow & 15)) << 4));
          oacc[dt] = __builtin_amdgcn_mfma_f32_32x32x16_bf16(af, vf, oacc[dt], 0, 0, 0);
        }
        __builtin_amdgcn_s_setprio(0);
      }
    }
    __syncthreads();
    cur ^= 1;
  }

  float tot = lsum + __shfl_xor(lsum, 32, 64);
  if (lane < 32) lsLS[w][q5] = (tot > 0.f) ? 1.f / tot : 0.f;
  asm volatile("s_waitcnt lgkmcnt(0)" ::: "memory");
  __builtin_amdgcn_sched_barrier(0);
#pragma unroll
  for (int rb = 0; rb < 4; rb++) {
    f32x4 inv4 = *(const f32x4*)(&lsLS[w][rb * 8 + hi * 4]);
#pragma unroll
    for (int j = 0; j < 4; j++) {
      int reg = rb * 4 + j;
      int qo = t0 + w * 32 + rb * 8 + hi * 4 + j;
#pragma unroll
      for (int dt = 0; dt < 2; dt++) {
        ow[((size_t)b * 1024 + qo) * 512 + h * 64 + dt * 32 + q5] =
            cvt1(oacc[dt][reg] * inv4[j]);
      }
    }
  }
}

extern "C" void kernel_launch(void* const* d_in, const int* in_sizes, int n_in,
                              void* d_out, int out_size, void* d_ws, size_t ws_size,
                              hipStream_t stream) {
  const float* query = (const float*)d_in[0];
  const float* key = (const float*)d_in[1];
  const float* value = (const float*)d_in[2];
  const int* amask = (const int*)d_in[3];
  const float* pos = (const float*)d_in[4];
  const float* Wq = (const float*)d_in[5];
  const float* bq = (const float*)d_in[6];
  const float* Wk = (const float*)d_in[7];
  const float* bk = (const float*)d_in[8];
  const float* Wv = (const float*)d_in[9];
  const float* bv = (const float*)d_in[10];
  const float* Wpos = (const float*)d_in[11];
  const float* Wout = (const float*)d_in[12];
  const float* bout = (const float*)d_in[13];
  const float* pbu = (const float*)d_in[14];
  const float* pbv = (const float*)d_in[15];

  float* out = (float*)d_out;
  float* cache = out + (size_t)8192 * 512;

  char* ws = (char*)d_ws;
  const size_t SZ = 8388608;
  dim3 blk(256);

  unsigned short* Woutb = (unsigned short*)(ws);               // slot 0 (2.1 MB)
  unsigned short* ws_q = (unsigned short*)(ws + 4 * SZ);
  unsigned short* ws_kp = (unsigned short*)(ws + 5 * SZ);
  unsigned short* ws_vt = (unsigned short*)(ws + 6 * SZ);
  unsigned short* ws_o = (unsigned short*)(ws + 7 * SZ);
  unsigned short* W4 = ws_o;                                   // dead before attn
  float* cbuf = (float*)(ws + 8 * SZ);
  unsigned long long* mbits = (unsigned long long*)(ws + 8 * SZ + 262144);

  prep_misc<<<dim3(33408), blk, 0, stream>>>(
      amask, mbits, Wq, Wk, Wv, Wpos, W4, Wout, Woutb);
  gemm_qkvp<<<dim3(512), dim3(512), 0, stream>>>(
      query, key, value, pos, W4, bq, bk, bv, ws_q, cache, ws_vt, ws_kp);
  fuse_kp<<<dim3(4096), blk, 0, stream>>>(cache, ws_kp, pbu, pbv, cbuf);
  attn_kernel<<<dim3(512), blk, 0, stream>>>(ws_q, ws_kp, ws_vt, cbuf, mbits, ws_o);
  gemm_out<<<dim3(128, 4), blk, 0, stream>>>(ws_o, Woutb, bout, out);
}

// Round 25
// 104.183 us; speedup vs baseline: 1.0165x; 1.0165x over previous
//
#include <hip/hip_runtime.h>

typedef __attribute__((ext_vector_type(8))) short bf16x8;
typedef __attribute__((ext_vector_type(4))) float f32x4;
typedef __attribute__((ext_vector_type(16))) float f32x16;
typedef __attribute__((ext_vector_type(4))) unsigned int u32x4;
typedef __attribute__((ext_vector_type(4))) unsigned short u16x4;

#define DEVFN static __device__ __forceinline__

DEVFN unsigned cvtpk(float lo, float hi) {
  unsigned r;
  asm("v_cvt_pk_bf16_f32 %0, %1, %2" : "=v"(r) : "v"(lo), "v"(hi));
  return r;
}
DEVFN unsigned short cvt1(float x) {
  unsigned r;
  asm("v_cvt_pk_bf16_f32 %0, %1, %1" : "=v"(r) : "v"(x));
  return (unsigned short)r;
}
DEVFN float fexp2(float x) {
  float r;
  asm("v_exp_f32 %0, %1" : "=v"(r) : "v"(x));
  return r;
}
DEVFN float bf2f(unsigned short s) { return __uint_as_float(((unsigned)s) << 16); }

DEVFN void gld16(const void* g, void* l) {
  __builtin_amdgcn_global_load_lds(
      (const __attribute__((address_space(1))) unsigned int*)g,
      (__attribute__((address_space(3))) unsigned int*)l, 16, 0, 0);
}

// barrier that orders LDS *reads* only: lgkm drain, leaves VMEM in flight
DEVFN void lds_read_barrier() {
  asm volatile("s_waitcnt lgkmcnt(0)" ::: "memory");
  __builtin_amdgcn_sched_barrier(0);
  __builtin_amdgcn_s_barrier();
  __builtin_amdgcn_sched_barrier(0);
}

// fused: mask packing (blocks 0..32767) + 5 weight-matrix f32->bf16 casts
__global__ __launch_bounds__(256, 8) void prep_misc(
    const int* __restrict__ m, unsigned long long* __restrict__ mb,
    const float* __restrict__ w0, const float* __restrict__ w1,
    const float* __restrict__ w2, const float* __restrict__ w3,
    unsigned short* __restrict__ w4dst,
    const float* __restrict__ wout, unsigned short* __restrict__ woutdst) {
  int bid = blockIdx.x;
  int tid = threadIdx.x;
  if (bid < 32768) {
    int word = bid * 4 + (tid >> 6);
    int lane = tid & 63;
    int v = m[(size_t)(word >> 4) * 1024 + (word & 15) * 64 + lane];
    unsigned long long bal = __ballot(v != 0);
    if (lane == 0) mb[word] = bal;
    return;
  }
  int pid = bid - 32768;  // 0..639
  const float* s;
  unsigned short* d;
  size_t off;
  if (pid < 512) {
    int y = pid >> 7;
    s = (y == 0) ? w0 : (y == 1) ? w1 : (y == 2) ? w2 : w3;
    d = w4dst + (size_t)y * 262144;
    off = (size_t)(pid & 127) * 2048 + (size_t)tid * 8;
  } else {
    s = wout;
    d = woutdst;
    off = (size_t)(pid - 512) * 2048 + (size_t)tid * 8;
  }
  float4 a = *(const float4*)(s + off);
  float4 b = *(const float4*)(s + off + 4);
  uint4 o;
  o.x = cvtpk(a.x, a.y); o.y = cvtpk(a.z, a.w);
  o.z = cvtpk(b.x, b.y); o.w = cvtpk(b.z, b.w);
  *(uint4*)(d + off) = o;
}

// ---- qkvp GEMM (R21 structure + lgkm-only barrier1): fused f32-A cast,
// tile 128x256, BK=64, 8 waves, A single-buffered reg staging, B
// double-buffered gld16. 80KB LDS, grid 512 XCD-swizzled.
__global__ __launch_bounds__(512, 2) void gemm_qkvp(
    const float* __restrict__ A0, const float* __restrict__ A1,
    const float* __restrict__ A2, const float* __restrict__ A3,
    const unsigned short* __restrict__ Wb, const float* __restrict__ b0,
    const float* __restrict__ b1, const float* __restrict__ b2,
    unsigned short* __restrict__ qout, float* __restrict__ cache,
    unsigned short* __restrict__ vtout, unsigned short* __restrict__ pout) {
  __shared__ alignas(16) char Als[128 * 128];
  __shared__ alignas(16) char Bls[2][256 * 128];
  const int tid = threadIdx.x;
  const int lane = tid & 63, w = tid >> 6;
  const int wr = (w >> 2) * 64, wc = (w & 3) * 64;
  const int lg = lane >> 4, lr = lane & 15;
  int id = blockIdx.x;
  int xcd = id & 7, j = id >> 3;
  const int n0 = (j & 1) * 256;
  const int mz = (j >> 1) & 3;
  const int m0 = (xcd * 8 + (j >> 3)) * 128;
  const float* Ap = (mz == 1) ? A1 : (mz == 2) ? A2 : (mz == 3) ? A3 : A0;
  const unsigned short* Wp = Wb + (size_t)mz * 262144;
  const float* bias = (mz == 0) ? b0 : (mz == 1) ? b1 : (mz == 2) ? b2 : nullptr;

  float4 ra[4];
  auto loadA = [&](int k0) {
#pragma unroll
    for (int rep = 0; rep < 2; rep++) {
      int cid = rep * 512 + tid;
      int row = cid >> 3, c = cid & 7;
      const float* src = Ap + (size_t)(m0 + row) * 512 + k0 + c * 8;
      ra[rep * 2] = *(const float4*)(src);
      ra[rep * 2 + 1] = *(const float4*)(src + 4);
    }
  };
  auto writeA = [&]() {
#pragma unroll
    for (int rep = 0; rep < 2; rep++) {
      int cid = rep * 512 + tid;
      int row = cid >> 3, c = cid & 7;
      uint4 o;
      o.x = cvtpk(ra[rep * 2].x, ra[rep * 2].y);
      o.y = cvtpk(ra[rep * 2].z, ra[rep * 2].w);
      o.z = cvtpk(ra[rep * 2 + 1].x, ra[rep * 2 + 1].y);
      o.w = cvtpk(ra[rep * 2 + 1].z, ra[rep * 2 + 1].w);
      *(uint4*)(Als + row * 128 + ((c ^ (row & 7)) << 4)) = o;
    }
  };
  auto stageB = [&](int buf, int k0) {
#pragma unroll
    for (int rep = 0; rep < 4; rep++) {
      int cid = rep * 512 + tid;
      int row = cid >> 3, c = cid & 7;
      gld16(Wp + (size_t)(n0 + row) * 512 + k0 + ((c ^ (row & 7)) << 3),
            Bls[buf] + ((rep * 512 + (w << 6)) << 4));
    }
  };

  f32x4 acc[4][4];
#pragma unroll
  for (int i = 0; i < 4; i++)
#pragma unroll
    for (int jj = 0; jj < 4; jj++) acc[i][jj] = (f32x4)(0.f);

  loadA(0);
  writeA();
  stageB(0, 0);
  __syncthreads();
  int cur = 0;
  for (int k0 = 0; k0 < 512; k0 += 64) {
    bool more = (k0 + 64 < 512);
    if (more) {
      loadA(k0 + 64);            // A(k+1) -> regs (private; may cross barrier1)
      stageB(cur ^ 1, k0 + 64);  // B(k+1) -> other buffer (may cross barrier1)
    }
#pragma unroll
    for (int ks = 0; ks < 2; ks++) {
      bf16x8 af[4], bfr[4];
#pragma unroll
      for (int i = 0; i < 4; i++) {
        int row = wr + i * 16 + lr;
        af[i] = *(const bf16x8*)(Als + row * 128 + (((ks * 4 + lg) ^ (row & 7)) << 4));
      }
#pragma unroll
      for (int jj = 0; jj < 4; jj++) {
        int row = wc + jj * 16 + lr;
        bfr[jj] = *(const bf16x8*)(Bls[cur] + row * 128 + (((ks * 4 + lg) ^ (row & 7)) << 4));
      }
#pragma unroll
      for (int i = 0; i < 4; i++)
#pragma unroll
        for (int jj = 0; jj < 4; jj++)
          acc[i][jj] = __builtin_amdgcn_mfma_f32_16x16x32_bf16(af[i], bfr[jj],
                                                               acc[i][jj], 0, 0, 0);
    }
    if (more) {
      lds_read_barrier();        // orders Als reads only; VMEM stays in flight
      writeA();                  // waits (counted) on its own A-reg loads
      __syncthreads();           // full drain: Als + B(k+1) ready
      cur ^= 1;
    }
  }

#pragma unroll
  for (int i = 0; i < 4; i++) {
#pragma unroll
    for (int jj = 0; jj < 4; jj++) {
      int colg = n0 + wc + jj * 16 + lr;
      float bc = bias ? bias[colg] : 0.f;
      int rbase = m0 + wr + i * 16 + lg * 4;
      int b = rbase >> 10, t = rbase & 1023, h = colg >> 6, dk = colg & 63;
      size_t bht = (size_t)(b * 8 + h) * 1024 + t;
      if (mz == 0) {
#pragma unroll
        for (int r = 0; r < 4; r++) qout[(bht + r) * 64 + dk] = cvt1(acc[i][jj][r] + bc);
      } else if (mz == 1) {
#pragma unroll
        for (int r = 0; r < 4; r++) cache[(bht + r) * 128 + dk] = acc[i][jj][r] + bc;
      } else if (mz == 3) {
#pragma unroll
        for (int r = 0; r < 4; r++) pout[(bht + r) * 64 + dk] = cvt1(acc[i][jj][r]);
      } else {
        float vv[4];
#pragma unroll
        for (int r = 0; r < 4; r++) {
          vv[r] = acc[i][jj][r] + bc;
          cache[(bht + r) * 128 + 64 + dk] = vv[r];
        }
        uint2 pv;
        pv.x = cvtpk(vv[0], vv[1]);
        pv.y = cvtpk(vv[2], vv[3]);
        *(uint2*)(vtout + ((size_t)(b * 8 + h) * 64 + dk) * 1024 + t) = pv;
      }
    }
  }
}

// ---- out-GEMM (lgkm-only barrier1): 64x128 tile, 4 waves,
// 40KB LDS, grid (128,4) -> 2 blocks/CU.
__global__ __launch_bounds__(256, 4) void gemm_out(
    const unsigned short* __restrict__ Ab, const unsigned short* __restrict__ Wp,
    const float* __restrict__ bias, float* __restrict__ fout) {
  __shared__ alignas(16) char Als[64 * 128];
  __shared__ alignas(16) char Bls[2][128 * 128];
  const int tid = threadIdx.x;
  const int lane = tid & 63, w = tid >> 6;
  const int wr = (w >> 1) * 32, wc = (w & 1) * 64;
  const int lg = lane >> 4, lr = lane & 15;
  const int m0 = blockIdx.x * 64, n0 = blockIdx.y * 128;

  auto stageA = [&](int k0) {
#pragma unroll
    for (int rep = 0; rep < 2; rep++) {
      int cid = rep * 256 + tid;
      int row = cid >> 3, c = cid & 7;
      gld16(Ab + (size_t)(m0 + row) * 512 + k0 + ((c ^ (row & 7)) << 3),
            Als + ((rep * 256 + (w << 6)) << 4));
    }
  };
  auto stageB = [&](int buf, int k0) {
#pragma unroll
    for (int rep = 0; rep < 4; rep++) {
      int cid = rep * 256 + tid;
      int row = cid >> 3, c = cid & 7;
      gld16(Wp + (size_t)(n0 + row) * 512 + k0 + ((c ^ (row & 7)) << 3),
            Bls[buf] + ((rep * 256 + (w << 6)) << 4));
    }
  };

  f32x4 acc[2][4];
#pragma unroll
  for (int i = 0; i < 2; i++)
#pragma unroll
    for (int j = 0; j < 4; j++) acc[i][j] = (f32x4)(0.f);

  stageA(0);
  stageB(0, 0);
  __syncthreads();
  int cur = 0;
  for (int k0 = 0; k0 < 512; k0 += 64) {
    bool more = (k0 + 64 < 512);
    if (more) stageB(cur ^ 1, k0 + 64);
#pragma unroll
    for (int ks = 0; ks < 2; ks++) {
      bf16x8 af[2], bfr[4];
#pragma unroll
      for (int i = 0; i < 2; i++) {
        int row = wr + i * 16 + lr;
        af[i] = *(const bf16x8*)(Als + row * 128 + (((ks * 4 + lg) ^ (row & 7)) << 4));
      }
#pragma unroll
      for (int j = 0; j < 4; j++) {
        int row = wc + j * 16 + lr;
        bfr[j] = *(const bf16x8*)(Bls[cur] + row * 128 + (((ks * 4 + lg) ^ (row & 7)) << 4));
      }
#pragma unroll
      for (int i = 0; i < 2; i++)
#pragma unroll
        for (int j = 0; j < 4; j++)
          acc[i][j] = __builtin_amdgcn_mfma_f32_16x16x32_bf16(af[i], bfr[j],
                                                              acc[i][j], 0, 0, 0);
    }
    if (more) {
      lds_read_barrier();        // reads of Als done; B(k+1) stays in flight
      stageA(k0 + 64);           // gld16 overwrite of Als
      __syncthreads();           // full drain
      cur ^= 1;
    }
  }

#pragma unroll
  for (int i = 0; i < 2; i++) {
#pragma unroll
    for (int j = 0; j < 4; j++) {
      int colg = n0 + wc + j * 16 + lr;
      float bc = bias[colg];
#pragma unroll
      for (int r = 0; r < 4; r++) {
        int rowg = m0 + wr + i * 16 + lg * 4 + r;
        fout[(size_t)rowg * 512 + colg] = acc[i][j][r] + bc;
      }
    }
  }
}

__global__ __launch_bounds__(256, 4) void fuse_kp(
    const float* __restrict__ kcache, unsigned short* __restrict__ kp,
    const float* __restrict__ ub, const float* __restrict__ vb,
    float* __restrict__ cb) {
  int tid = threadIdx.x;
  int row = blockIdx.x * 16 + (tid >> 4);
  int g = tid & 15;
  int h = (row >> 10) & 7;
  float4 k4 = *(const float4*)(kcache + (size_t)row * 128 + g * 4);
  u16x4 p4 = *(const u16x4*)(kp + (size_t)row * 64 + g * 4);
  float4 uu = *(const float4*)(ub + h * 64 + g * 4);
  float4 vv = *(const float4*)(vb + h * 64 + g * 4);
  float kf[4] = {k4.x, k4.y, k4.z, k4.w};
  float uf[4] = {uu.x, uu.y, uu.z, uu.w};
  float vf[4] = {vv.x, vv.y, vv.z, vv.w};
  float part = 0.f;
  float s[4];
#pragma unroll
  for (int j = 0; j < 4; j++) {
    float pf = bf2f((unsigned short)p4[j]);
    s[j] = kf[j] + pf;
    part += uf[j] * kf[j] + vf[j] * pf;
  }
  uint2 o;
  o.x = cvtpk(s[0], s[1]);
  o.y = cvtpk(s[2], s[3]);
  *(uint2*)(kp + (size_t)row * 64 + g * 4) = o;
#pragma unroll
  for (int sft = 1; sft < 16; sft <<= 1) part += __shfl_xor(part, sft, 64);
  if (g == 0) cb[row] = part;
}

// flash attn, m214-style: 32x32x16 MFMA, swapped QK (S^T in regs),
// in-register softmax, P->A-frag via cvt_pk + __shfl_xor(32) (no P LDS
// roundtrip). 4 waves x 32 q-rows, KVBLK=128 dbuf, grid 512 XCD-swizzled.
__global__ __launch_bounds__(256, 2) void attn_kernel(
    const unsigned short* __restrict__ qw, const unsigned short* __restrict__ kpw,
    const unsigned short* __restrict__ vtw, const float* __restrict__ cb,
    const unsigned long long* __restrict__ mbits, unsigned short* __restrict__ ow) {
  __shared__ alignas(16) char KPls[2][128 * 128];
  __shared__ alignas(16) char VTls[2][64 * 256];
  __shared__ alignas(16) float cvLS[1024];
  __shared__ alignas(16) float lsLS[4][32];

  const int tid = threadIdx.x;
  const int lane = tid & 63, w = tid >> 6;
  const int hi = lane >> 5, q5 = lane & 31;
  const int l = blockIdx.x;
  const int bh = (l & 7) * 8 + ((l >> 3) >> 3);
  const int t0 = ((l >> 3) & 7) * 128;
  const int b = bh >> 3;
  const int h = bh & 7;
  const float NEG = -3.0e38f;
  const float SC = 0.125f * 1.44269504088896f;
  const float MREF = 24.0f;

#pragma unroll
  for (int i = 0; i < 4; i++)
    cvLS[i * 256 + tid] = cb[(size_t)bh * 1024 + i * 256 + tid] * SC - MREF;

  const int qg = t0 + w * 32 + q5;
  const size_t qrow = (size_t)bh * 1024 + qg;
  bf16x8 qf[4];
#pragma unroll
  for (int ks = 0; ks < 4; ks++)
    qf[ks] = *(const bf16x8*)(qw + qrow * 64 + ks * 16 + hi * 8);

  bool wave_full;
  {
    unsigned long long accm = ~0ull;
#pragma unroll
    for (int j = 0; j < 8; j++)
      accm &= mbits[((size_t)b * 1024 + qg) * 16 + hi * 8 + j];
    wave_full = __all(accm == ~0ull);
  }

  f32x16 oacc[2];
#pragma unroll
  for (int dt = 0; dt < 2; dt++) oacc[dt] = (f32x16)(0.f);
  float mrow = 0.f, lsum = 0.f;

  auto stage = [&](int buf, int s0) {
    const size_t kr0 = (size_t)bh * 1024 + s0;
#pragma unroll
    for (int p = 0; p < 4; p++) {
      int row = p * 32 + (tid >> 3), c = tid & 7;
      gld16(kpw + (kr0 + row) * 64 + ((c ^ (row & 7)) << 3),
            KPls[buf] + p * 4096 + w * 1024);
    }
#pragma unroll
    for (int p = 0; p < 4; p++) {
      int row = p * 16 + (tid >> 4), c = tid & 15;
      gld16(vtw + ((size_t)bh * 64 + row) * 1024 + s0 + ((c ^ (row & 15)) << 3),
            VTls[buf] + p * 4096 + w * 1024);
    }
  };

  stage(0, 0);
  __syncthreads();
  int cur = 0;
  for (int it = 0; it < 8; ++it) {
    const int s0 = it * 128;
    if (it < 7) stage(cur ^ 1, s0 + 128);

#pragma unroll
    for (int t = 0; t < 4; t++) {
      f32x16 sacc = (f32x16)(0.f);
      const int arow = t * 32 + q5;
      __builtin_amdgcn_s_setprio(1);
#pragma unroll
      for (int ks = 0; ks < 4; ks++) {
        bf16x8 kf = *(const bf16x8*)(KPls[cur] + arow * 128 +
                                     (((ks * 2 + hi) ^ (arow & 7)) << 4));
        sacc = __builtin_amdgcn_mfma_f32_32x32x16_bf16(kf, qf[ks], sacc, 0, 0, 0);
      }
      __builtin_amdgcn_s_setprio(0);

      float p[16];
      if (wave_full) {
        float ls = 0.f;
#pragma unroll
        for (int rb = 0; rb < 4; rb++) {
          f32x4 cv4 = *(const f32x4*)(cvLS + s0 + t * 32 + rb * 8 + hi * 4);
#pragma unroll
          for (int j = 0; j < 4; j++) {
            int reg = rb * 4 + j;
            p[reg] = fexp2(fmaf(sacc[reg], SC, cv4[j]));
            ls += p[reg];
          }
        }
        lsum += ls;
      } else {
        unsigned long long mw =
            mbits[((size_t)b * 1024 + qg) * 16 + ((s0 + t * 32) >> 6)];
        const int bbase = (t & 1) * 32;
        float s_[16];
        float mx = NEG;
#pragma unroll
        for (int rb = 0; rb < 4; rb++) {
          f32x4 cv4 = *(const f32x4*)(cvLS + s0 + t * 32 + rb * 8 + hi * 4);
#pragma unroll
          for (int j = 0; j < 4; j++) {
            int reg = rb * 4 + j;
            s_[reg] = fmaf(sacc[reg], SC, cv4[j]);
            if ((mw >> (bbase + rb * 8 + hi * 4 + j)) & 1ull)
              mx = fmaxf(mx, s_[reg]);
          }
        }
        mx = fmaxf(mx, __shfl_xor(mx, 32, 64));
        float mn = fmaxf(mrow, mx);
        float sc = (mn == mrow) ? 1.f : fexp2(mrow - mn);
        mrow = mn;
        lsum *= sc;
#pragma unroll
        for (int rb = 0; rb < 4; rb++)
#pragma unroll
          for (int j = 0; j < 4; j++) {
            int reg = rb * 4 + j;
            bool on = (mw >> (bbase + rb * 8 + hi * 4 + j)) & 1ull;
            p[reg] = on ? fexp2(s_[reg] - mn) : 0.f;
            lsum += p[reg];
          }
        if (lane < 32) lsLS[w][q5] = sc;
        asm volatile("s_waitcnt lgkmcnt(0)" ::: "memory");
        __builtin_amdgcn_sched_barrier(0);
#pragma unroll
        for (int rb = 0; rb < 4; rb++) {
          f32x4 s4 = *(const f32x4*)(&lsLS[w][rb * 8 + hi * 4]);
#pragma unroll
          for (int j = 0; j < 4; j++) {
#pragma unroll
            for (int dt = 0; dt < 2; dt++) oacc[dt][rb * 4 + j] *= s4[j];
          }
        }
      }

#pragma unroll
      for (int ks16 = 0; ks16 < 2; ks16++) {
        unsigned a0 = cvtpk(p[ks16 * 8 + 0], p[ks16 * 8 + 1]);
        unsigned a1 = cvtpk(p[ks16 * 8 + 2], p[ks16 * 8 + 3]);
        unsigned b0 = cvtpk(p[ks16 * 8 + 4], p[ks16 * 8 + 5]);
        unsigned b1 = cvtpk(p[ks16 * 8 + 6], p[ks16 * 8 + 7]);
        unsigned xa0 = __shfl_xor(a0, 32, 64);
        unsigned xa1 = __shfl_xor(a1, 32, 64);
        unsigned xb0 = __shfl_xor(b0, 32, 64);
        unsigned xb1 = __shfl_xor(b1, 32, 64);
        u32x4 pk4;
        pk4.x = hi ? xb0 : a0;
        pk4.y = hi ? xb1 : a1;
        pk4.z = hi ? b0 : xa0;
        pk4.w = hi ? b1 : xa1;
        bf16x8 af = __builtin_bit_cast(bf16x8, pk4);
        __builtin_amdgcn_s_setprio(1);
#pragma unroll
        for (int dt = 0; dt < 2; dt++) {
          int vrow = dt * 32 + q5;
          int vc = t * 4 + ks16 * 2 + hi;
          bf16x8 vf = *(const bf16x8*)(VTls[cur] + vrow * 256 +
                                       ((vc ^ (vrow & 15)) << 4));
          oacc[dt] = __builtin_amdgcn_mfma_f32_32x32x16_bf16(af, vf, oacc[dt], 0, 0, 0);
        }
        __builtin_amdgcn_s_setprio(0);
      }
    }
    __syncthreads();
    cur ^= 1;
  }

  float tot = lsum + __shfl_xor(lsum, 32, 64);
  if (lane < 32) lsLS[w][q5] = (tot > 0.f) ? 1.f / tot : 0.f;
  asm volatile("s_waitcnt lgkmcnt(0)" ::: "memory");
  __builtin_amdgcn_sched_barrier(0);
#pragma unroll
  for (int rb = 0; rb < 4; rb++) {
    f32x4 inv4 = *(const f32x4*)(&lsLS[w][rb * 8 + hi * 4]);
#pragma unroll
    for (int j = 0; j < 4; j++) {
      int reg = rb * 4 + j;
      int qo = t0 + w * 32 + rb * 8 + hi * 4 + j;
#pragma unroll
      for (int dt = 0; dt < 2; dt++) {
        ow[((size_t)b * 1024 + qo) * 512 + h * 64 + dt * 32 + q5] =
            cvt1(oacc[dt][reg] * inv4[j]);
      }
    }
  }
}

extern "C" void kernel_launch(void* const* d_in, const int* in_sizes, int n_in,
                              void* d_out, int out_size, void* d_ws, size_t ws_size,
                              hipStream_t stream) {
  const float* query = (const float*)d_in[0];
  const float* key = (const float*)d_in[1];
  const float* value = (const float*)d_in[2];
  const int* amask = (const int*)d_in[3];
  const float* pos = (const float*)d_in[4];
  const float* Wq = (const float*)d_in[5];
  const float* bq = (const float*)d_in[6];
  const float* Wk = (const float*)d_in[7];
  const float* bk = (const float*)d_in[8];
  const float* Wv = (const float*)d_in[9];
  const float* bv = (const float*)d_in[10];
  const float* Wpos = (const float*)d_in[11];
  const float* Wout = (const float*)d_in[12];
  const float* bout = (const float*)d_in[13];
  const float* pbu = (const float*)d_in[14];
  const float* pbv = (const float*)d_in[15];

  float* out = (float*)d_out;
  float* cache = out + (size_t)8192 * 512;

  char* ws = (char*)d_ws;
  const size_t SZ = 8388608;
  dim3 blk(256);

  unsigned short* Woutb = (unsigned short*)(ws);               // slot 0 (2.1 MB)
  unsigned short* ws_q = (unsigned short*)(ws + 4 * SZ);
  unsigned short* ws_kp = (unsigned short*)(ws + 5 * SZ);
  unsigned short* ws_vt = (unsigned short*)(ws + 6 * SZ);
  unsigned short* ws_o = (unsigned short*)(ws + 7 * SZ);
  unsigned short* W4 = ws_o;                                   // dead before attn
  float* cbuf = (float*)(ws + 8 * SZ);
  unsigned long long* mbits = (unsigned long long*)(ws + 8 * SZ + 262144);

  prep_misc<<<dim3(33408), blk, 0, stream>>>(
      amask, mbits, Wq, Wk, Wv, Wpos, W4, Wout, Woutb);
  gemm_qkvp<<<dim3(512), dim3(512), 0, stream>>>(
      query, key, value, pos, W4, bq, bk, bv, ws_q, cache, ws_vt, ws_kp);
  fuse_kp<<<dim3(4096), blk, 0, stream>>>(cache, ws_kp, pbu, pbv, cbuf);
  attn_kernel<<<dim3(512), blk, 0, stream>>>(ws_q, ws_kp, ws_vt, cbuf, mbits, ws_o);
  gemm_out<<<dim3(128, 4), blk, 0, stream>>>(ws_o, Woutb, bout, out);
}